// Round 6
// baseline (135.999 us; speedup 1.0000x reference)
//
#include <hip/hip_runtime.h>
#include <hip/hip_bf16.h>
#include <math.h>

#define NH 12
#define SEQ 1024
#define HD 64
#define HDIM 768
#define BSZ 4
#define RK 129
#define FMIN -3.4028234663852886e38f

typedef __attribute__((ext_vector_type(8))) short short8;
typedef __attribute__((ext_vector_type(4))) short short4v;
typedef __attribute__((ext_vector_type(8))) _Float16 f16x8;
typedef __attribute__((ext_vector_type(4))) float f32x4;

__device__ inline short f2bf(float x) {
    union { __hip_bfloat16 h; short s; } u;
    u.h = __float2bfloat16(x);
    return u.s;
}

__device__ inline void async_load16(void* lds, const void* g) {
    __builtin_amdgcn_global_load_lds(
        (const __attribute__((address_space(1))) unsigned int*)g,
        (__attribute__((address_space(3))) unsigned int*)lds, 16, 0, 0);
}

// ---------------- Kernel 0: prep = f16 convert (X, Ek) + Evt + W transpose --
#define NXCHUNK 393216   // 4096*768/8
#define NECHUNK 1032     // 129*64/8
#define NEVCHUNK 1280    // 64*160/8
#define NCONVB ((NXCHUNK + NECHUNK + NEVCHUNK + 255) / 256)   // 1548
#define NTRB   (144 * 3)                                      // 432
__global__ __launch_bounds__(256) void prep_kernel(
    const float* __restrict__ X, const float* __restrict__ Ek,
    const float* __restrict__ Ev,
    const float* __restrict__ Wq, const float* __restrict__ Wk, const float* __restrict__ Wv,
    _Float16* __restrict__ Xh, _Float16* __restrict__ Ekh, short* __restrict__ Evt,
    _Float16* __restrict__ Wtq, _Float16* __restrict__ Wtk, _Float16* __restrict__ Wtv)
{
    const int bidg = blockIdx.x;
    if (bidg < NCONVB) {
        int idx = bidg * 256 + threadIdx.x;
        if (idx < NXCHUNK + NECHUNK) {
            const float* src;
            _Float16* dst;
            if (idx < NXCHUNK) { src = X; dst = Xh; }
            else { idx -= NXCHUNK; src = Ek; dst = Ekh; }
            float4 a = ((const float4*)src)[idx * 2];
            float4 b = ((const float4*)src)[idx * 2 + 1];
            f16x8 o;
            o[0] = (_Float16)a.x; o[1] = (_Float16)a.y; o[2] = (_Float16)a.z; o[3] = (_Float16)a.w;
            o[4] = (_Float16)b.x; o[5] = (_Float16)b.y; o[6] = (_Float16)b.z; o[7] = (_Float16)b.w;
            ((f16x8*)dst)[idx] = o;
        } else if (idx < NXCHUNK + NECHUNK + NEVCHUNK) {
            idx -= NXCHUNK + NECHUNK;
            const int dim = idx / 20;
            const int r0  = (idx % 20) * 8;
            short8 o;
#pragma unroll
            for (int e = 0; e < 8; ++e) {
                int rel = r0 + e;
                float v = (rel < RK) ? Ev[(size_t)rel * HD + dim] : 0.0f;
                o[e] = f2bf(v);
            }
            *(short8*)&Evt[(size_t)dim * 160 + r0] = o;
        }
        return;
    }
    // ---- W transpose part ----
    const int bid2 = bidg - NCONVB;
    const int z = bid2 / 144;
    const int r = bid2 % 144;
    const float* __restrict__ W = (z == 0) ? Wq : (z == 1) ? Wk : Wv;
    _Float16* __restrict__ Wt   = (z == 0) ? Wtq : (z == 1) ? Wtk : Wtv;

    __shared__ float sT[64][65];
    const int t  = threadIdx.x;
    const int k0 = (r / 12) * 64;
    const int n0 = (r % 12) * 64;

    const int c  = (t & 15) * 4;
    const int kr = t >> 4;
#pragma unroll
    for (int rr = 0; rr < 4; ++rr) {
        float4 v = *(const float4*)&W[(size_t)(k0 + kr + rr * 16) * HDIM + n0 + c];
        sT[c + 0][kr + rr * 16] = v.x;
        sT[c + 1][kr + rr * 16] = v.y;
        sT[c + 2][kr + rr * 16] = v.z;
        sT[c + 3][kr + rr * 16] = v.w;
    }
    __syncthreads();
    const int rn = t >> 2;
    const int ck = (t & 3) * 16;
#pragma unroll
    for (int g = 0; g < 2; ++g) {
        f16x8 o;
#pragma unroll
        for (int e = 0; e < 8; ++e) o[e] = (_Float16)sT[rn][ck + g * 8 + e];
        *(f16x8*)&Wt[(size_t)(n0 + rn) * HDIM + k0 + ck + g * 8] = o;
    }
}

// ---------------- Kernel 1: QKV projection via f16 MFMA --------------------
// Q,K -> [bh][s][d] f16.  V -> TRANSPOSED [bh][d][s] bf16 (for direct PV B-frags).
__global__ __launch_bounds__(256) void qkv_mfma_kernel(
    const _Float16* __restrict__ Xh,
    const _Float16* __restrict__ Wtq, const _Float16* __restrict__ Wtk, const _Float16* __restrict__ Wtv,
    const float* __restrict__ bq, const float* __restrict__ bk, const float* __restrict__ bv,
    _Float16* __restrict__ Qo, _Float16* __restrict__ Ko, short* __restrict__ Vt)
{
    int bid = blockIdx.x;
    bid = (bid & 7) * 72 + (bid >> 3);          // XCD swizzle (576 = 8*72)
    const int which = bid / 192;
    const int rem   = bid % 192;
    const int n0    = (rem / 32) * 128;
    const int m0    = (rem % 32) * 128;
    const _Float16* __restrict__ Wt = (which == 0) ? Wtq : (which == 1) ? Wtk : Wtv;
    const float* __restrict__ bias  = (which == 0) ? bq : (which == 1) ? bk : bv;

    __shared__ __align__(16) _Float16 sA[128 * 64];
    __shared__ __align__(16) _Float16 sB[128 * 64];

    const int t  = threadIdx.x;
    const int w  = t >> 6, l = t & 63;
    const int lq = l & 15, lg = l >> 4;
    const int wr = w >> 1, wc = w & 1;

    f32x4 acc[4][4];
#pragma unroll
    for (int i = 0; i < 4; ++i)
#pragma unroll
        for (int j = 0; j < 4; ++j) acc[i][j] = (f32x4){0.f, 0.f, 0.f, 0.f};

    for (int k0 = 0; k0 < HDIM; k0 += 64) {
        __syncthreads();
#pragma unroll
        for (int r = 0; r < 4; ++r) {
            const int cib = r * 256 + w * 64;
            const int ci  = cib + l;
            const int row = ci >> 3, cr = ci & 7;
            const int lc  = cr ^ (row & 7);
            async_load16(&sA[(size_t)cib * 8],
                         &Xh[(size_t)(m0 + row) * HDIM + k0 + lc * 8]);
            async_load16(&sB[(size_t)cib * 8],
                         &Wt[(size_t)(n0 + row) * HDIM + k0 + lc * 8]);
        }
        __syncthreads();

        f16x8 af[4][2], bf[4][2];
#pragma unroll
        for (int i = 0; i < 4; ++i) {
#pragma unroll
            for (int ks = 0; ks < 2; ++ks) {
                int ra = wr * 64 + i * 16 + lq;
                af[i][ks] = *(const f16x8*)((const char*)sA +
                            ra * 128 + ((ks * 64 + lg * 16) ^ ((ra & 7) << 4)));
                int rb = wc * 64 + i * 16 + lq;
                bf[i][ks] = *(const f16x8*)((const char*)sB +
                            rb * 128 + ((ks * 64 + lg * 16) ^ ((rb & 7) << 4)));
            }
        }
#pragma unroll
        for (int i = 0; i < 4; ++i)
#pragma unroll
            for (int j = 0; j < 4; ++j) {
                acc[i][j] = __builtin_amdgcn_mfma_f32_16x16x32_f16(af[i][0], bf[j][0], acc[i][j], 0, 0, 0);
                acc[i][j] = __builtin_amdgcn_mfma_f32_16x16x32_f16(af[i][1], bf[j][1], acc[i][j], 0, 0, 0);
            }
    }

    _Float16* __restrict__ Yh = (which == 0) ? Qo : Ko;
#pragma unroll
    for (int i = 0; i < 4; ++i) {
        const int mb = m0 + wr * 64 + i * 16 + lg * 4;
        const int bb = mb >> 10, ss = mb & 1023;
#pragma unroll
        for (int j = 0; j < 4; ++j) {
            const int n  = n0 + wc * 64 + j * 16 + lq;
            const float bv4 = bias[n];
            const int hh = n >> 6, dd = n & 63;
            if (which == 2) {
                short4v pk;
#pragma unroll
                for (int reg = 0; reg < 4; ++reg)
                    pk[reg] = f2bf(acc[i][j][reg] + bv4);
                *(short4v*)&Vt[((size_t)(bb * NH + hh) * HD + dd) * SEQ + ss] = pk;
            } else {
#pragma unroll
                for (int reg = 0; reg < 4; ++reg) {
                    const size_t off = ((size_t)(bb * NH + hh) * SEQ + ss + reg) * HD + dd;
                    Yh[off] = (_Float16)(acc[i][j][reg] + bv4);
                }
            }
        }
    }
}

// ---------------- Kernel 2: barrier-free MFMA flash attention --------------
// 4 waves/block; each wave owns 16 q-rows and ONLY per-wave LDS.
// K and V^T B-fragments loaded directly from global with DEPTH-1 REGISTER
// PREFETCH: tile j+1's loads issue before tile j's compute (T14).
__global__ __launch_bounds__(256) void attn_mfma_kernel(
    const _Float16* __restrict__ Q, const _Float16* __restrict__ K,
    const short* __restrict__ Vt, const float* __restrict__ mask,
    const _Float16* __restrict__ Ekh, const short* __restrict__ Evt,
    float* __restrict__ out)
{
    __shared__ __align__(16) short sPscr[4][16][40];     // bf16 probs (PV A-frag)
    __shared__ __align__(16) _Float16 sPpos[4][16][132]; // Q@Ek^T
    __shared__ __align__(16) short sBand[4][16][168];    // bf16 band probs

    const int t  = threadIdx.x;
    const int w  = t >> 6;
    const int l  = t & 63;
    const int lq = l & 15;
    const int lg = l >> 4;
    const int b  = blockIdx.z;
    const int h  = blockIdx.y;
    const int i0 = blockIdx.x * 64;
    const int bh = b * NH + h;
    const int wrow0 = i0 + w * 16;

    // per-wave zero of own band buffer (no barrier needed anywhere)
    {
        short8 z8 = {0, 0, 0, 0, 0, 0, 0, 0};
        short8* p = (short8*)&sBand[w][0][0];
        for (int idx = l; idx < 336; idx += 64) p[idx] = z8;
    }

    const _Float16* qp = Q + ((size_t)bh * SEQ + wrow0 + lq) * HD;
    f16x8 qf0 = *(const f16x8*)&qp[lg * 8];
    f16x8 qf1 = *(const f16x8*)&qp[32 + lg * 8];

    // P_pos = Q @ E_key^T  (per-wave)
#pragma unroll
    for (int nt = 0; nt < 9; ++nt) {
        int cc = nt * 16 + lq;
        f16x8 eb0 = {0, 0, 0, 0, 0, 0, 0, 0};
        f16x8 eb1 = {0, 0, 0, 0, 0, 0, 0, 0};
        if (cc < RK) {
            eb0 = *(const f16x8*)&Ekh[(size_t)cc * HD + lg * 8];
            eb1 = *(const f16x8*)&Ekh[(size_t)cc * HD + 32 + lg * 8];
        }
        f32x4 pc = {0.f, 0.f, 0.f, 0.f};
        pc = __builtin_amdgcn_mfma_f32_16x16x32_f16(qf0, eb0, pc, 0, 0, 0);
        pc = __builtin_amdgcn_mfma_f32_16x16x32_f16(qf1, eb1, pc, 0, 0, 0);
        if (cc < 132) {
#pragma unroll
            for (int reg = 0; reg < 4; ++reg)
                sPpos[w][lg * 4 + reg][cc] = (_Float16)pc[reg];
        }
    }

    f32x4 acc[4];
#pragma unroll
    for (int nt = 0; nt < 4; ++nt) acc[nt] = (f32x4){0.f, 0.f, 0.f, 0.f};
    float lacc[4] = {0.f, 0.f, 0.f, 0.f};

    const _Float16* kbase = K + ((size_t)bh * SEQ + lq) * HD + lg * 8;
    const short*    vbase = Vt + ((size_t)bh * HD + lq) * SEQ + lg * 8;
    const float*    mbase = mask + (size_t)b * SEQ + lq;

    // prologue: tile 0 into current regs
    f16x8 kb00 = *(const f16x8*)&kbase[0];
    f16x8 kb01 = *(const f16x8*)&kbase[32];
    f16x8 kb10 = *(const f16x8*)&kbase[16 * HD];
    f16x8 kb11 = *(const f16x8*)&kbase[16 * HD + 32];
    short8 vb0 = *(const short8*)&vbase[0];
    short8 vb1 = *(const short8*)&vbase[16 * SEQ];
    short8 vb2 = *(const short8*)&vbase[32 * SEQ];
    short8 vb3 = *(const short8*)&vbase[48 * SEQ];
    float mt0 = (1.0f - mbase[0])  * FMIN;
    float mt1 = (1.0f - mbase[16]) * FMIN;

    for (int jt = 0; jt < SEQ / 32; ++jt) {
        const int j0 = jt * 32;
        const int jn = (jt + 1) & 31;          // wrap on last iter: harmless reload
        // ---- issue next tile's loads (consumed at loop bottom) ----
        const _Float16* kn = kbase + (size_t)jn * 32 * HD;
        const short*    vn = vbase + jn * 32;
        const float*    mn = mbase + jn * 32;
        f16x8 nk00 = *(const f16x8*)&kn[0];
        f16x8 nk01 = *(const f16x8*)&kn[32];
        f16x8 nk10 = *(const f16x8*)&kn[16 * HD];
        f16x8 nk11 = *(const f16x8*)&kn[16 * HD + 32];
        short8 nv0 = *(const short8*)&vn[0];
        short8 nv1 = *(const short8*)&vn[16 * SEQ];
        short8 nv2 = *(const short8*)&vn[32 * SEQ];
        short8 nv3 = *(const short8*)&vn[48 * SEQ];
        float nmt0 = (1.0f - mn[0])  * FMIN;
        float nmt1 = (1.0f - mn[16]) * FMIN;

        // ---- compute with current regs ----
        f32x4 sc0 = {0.f, 0.f, 0.f, 0.f};
        f32x4 sc1 = {0.f, 0.f, 0.f, 0.f};
        sc0 = __builtin_amdgcn_mfma_f32_16x16x32_f16(qf0, kb00, sc0, 0, 0, 0);
        sc0 = __builtin_amdgcn_mfma_f32_16x16x32_f16(qf1, kb01, sc0, 0, 0, 0);
        sc1 = __builtin_amdgcn_mfma_f32_16x16x32_f16(qf0, kb10, sc1, 0, 0, 0);
        sc1 = __builtin_amdgcn_mfma_f32_16x16x32_f16(qf1, kb11, sc1, 0, 0, 0);

        const bool band_active = (j0 + 31 >= wrow0 - 64) && (j0 <= wrow0 + 15 + 64);
        if (band_active) {
#pragma unroll
            for (int ct = 0; ct < 2; ++ct) {
                const f32x4 sc = ct ? sc1 : sc0;
                const float mt = ct ? mt1 : mt0;
                const int relb = j0 + ct * 16 + lq - wrow0 - lg * 4 + 64;
#pragma unroll
                for (int reg = 0; reg < 4; ++reg) {
                    const int row = lg * 4 + reg;
                    const int rel = relb - reg;
                    float s = sc[reg] + mt;
                    const bool inb = ((unsigned)rel < (unsigned)RK);
                    if (inb) s += (float)sPpos[w][row][rel];
                    const float p = __expf(s);
                    lacc[reg] += p;
                    const short pb = f2bf(p);
                    sPscr[w][row][ct * 16 + lq] = pb;
                    if (inb) sBand[w][row][rel] = pb;
                }
            }
        } else {
#pragma unroll
            for (int ct = 0; ct < 2; ++ct) {
                const f32x4 sc = ct ? sc1 : sc0;
                const float mt = ct ? mt1 : mt0;
#pragma unroll
                for (int reg = 0; reg < 4; ++reg) {
                    const float p = __expf(sc[reg] + mt);
                    lacc[reg] += p;
                    sPscr[w][lg * 4 + reg][ct * 16 + lq] = f2bf(p);
                }
            }
        }

        // PV (wave-internal LDS RAW; compiler inserts lgkmcnt waits)
        short8 pa = *(const short8*)&sPscr[w][lq][lg * 8];
        acc[0] = __builtin_amdgcn_mfma_f32_16x16x32_bf16(pa, vb0, acc[0], 0, 0, 0);
        acc[1] = __builtin_amdgcn_mfma_f32_16x16x32_bf16(pa, vb1, acc[1], 0, 0, 0);
        acc[2] = __builtin_amdgcn_mfma_f32_16x16x32_bf16(pa, vb2, acc[2], 0, 0, 0);
        acc[3] = __builtin_amdgcn_mfma_f32_16x16x32_bf16(pa, vb3, acc[3], 0, 0, 0);

        // ---- rotate prefetch regs ----
        kb00 = nk00; kb01 = nk01; kb10 = nk10; kb11 = nk11;
        vb0 = nv0; vb1 = nv1; vb2 = nv2; vb3 = nv3;
        mt0 = nmt0; mt1 = nmt1;
    }

    float linv[4];
#pragma unroll
    for (int reg = 0; reg < 4; ++reg) {
        float lr = lacc[reg];
        lr += __shfl_xor(lr, 1);
        lr += __shfl_xor(lr, 2);
        lr += __shfl_xor(lr, 4);
        lr += __shfl_xor(lr, 8);
        linv[reg] = 1.0f / lr;
    }

    // band value term via MFMA: acc[nt] += bandP[16x160] @ Evt^T[160x64]
    short8 bandA[5];
#pragma unroll
    for (int ks = 0; ks < 5; ++ks)
        bandA[ks] = *(const short8*)&sBand[w][lq][ks * 32 + lg * 8];
#pragma unroll
    for (int nt = 0; nt < 4; ++nt) {
#pragma unroll
        for (int ks = 0; ks < 5; ++ks) {
            short8 eb = *(const short8*)&Evt[(size_t)(nt * 16 + lq) * 160 + ks * 32 + lg * 8];
            acc[nt] = __builtin_amdgcn_mfma_f32_16x16x32_bf16(bandA[ks], eb, acc[nt], 0, 0, 0);
        }
    }

#pragma unroll
    for (int nt = 0; nt < 4; ++nt) {
#pragma unroll
        for (int reg = 0; reg < 4; ++reg) {
            int qi = wrow0 + lg * 4 + reg;
            out[((size_t)b * SEQ + qi) * HDIM + h * HD + nt * 16 + lq] =
                acc[nt][reg] * linv[reg];
        }
    }
}

extern "C" void kernel_launch(void* const* d_in, const int* in_sizes, int n_in,
                              void* d_out, int out_size, void* d_ws, size_t ws_size,
                              hipStream_t stream) {
    const float* X    = (const float*)d_in[0];
    const float* mask = (const float*)d_in[1];
    const float* Wq   = (const float*)d_in[2];
    const float* bq   = (const float*)d_in[3];
    const float* Wk   = (const float*)d_in[4];
    const float* bk   = (const float*)d_in[5];
    const float* Wv   = (const float*)d_in[6];
    const float* bv   = (const float*)d_in[7];
    const float* Ek   = (const float*)d_in[8];
    const float* Ev   = (const float*)d_in[9];
    float* out        = (float*)d_out;

    char* ws = (char*)d_ws;
    const size_t SZ_QKV = (size_t)BSZ * NH * SEQ * HD * 2;   // 6,291,456 B each
    const size_t SZ_W   = (size_t)HDIM * HDIM * 2;           // 1,179,648 B each
    _Float16* Qh  = (_Float16*)(ws);
    _Float16* Kh  = (_Float16*)(ws + SZ_QKV);
    short*    Vt  = (short*)   (ws + 2 * SZ_QKV);            // [bh][d][s] bf16
    _Float16* Xh  = (_Float16*)(ws + 3 * SZ_QKV);
    _Float16* Wtq = (_Float16*)(ws + 4 * SZ_QKV);
    _Float16* Wtk = (_Float16*)(ws + 4 * SZ_QKV + SZ_W);
    _Float16* Wtv = (_Float16*)(ws + 4 * SZ_QKV + 2 * SZ_W);
    _Float16* Ekh = (_Float16*)(ws + 4 * SZ_QKV + 3 * SZ_W);
    short*    Evt = (short*)   (ws + 4 * SZ_QKV + 3 * SZ_W + 20480);

    prep_kernel<<<NCONVB + NTRB, 256, 0, stream>>>(
        X, Ek, Ev, Wq, Wk, Wv, Xh, Ekh, Evt, Wtq, Wtk, Wtv);
    qkv_mfma_kernel<<<576, 256, 0, stream>>>(Xh, Wtq, Wtk, Wtv, bq, bk, bv, Qh, Kh, Vt);
    attn_mfma_kernel<<<dim3(SEQ / 64, NH, BSZ), 256, 0, stream>>>(Qh, Kh, Vt, mask, Ekh, Evt, out);
}

// Round 7
// 134.819 us; speedup vs baseline: 1.0087x; 1.0087x over previous
//
#include <hip/hip_runtime.h>
#include <hip/hip_bf16.h>
#include <math.h>

#define NH 12
#define SEQ 1024
#define HD 64
#define HDIM 768
#define BSZ 4
#define RK 129
#define FMIN -3.4028234663852886e38f

typedef __attribute__((ext_vector_type(8))) short short8;
typedef __attribute__((ext_vector_type(4))) short short4v;
typedef __attribute__((ext_vector_type(8))) _Float16 f16x8;
typedef __attribute__((ext_vector_type(4))) float f32x4;

__device__ inline short f2bf(float x) {
    union { __hip_bfloat16 h; short s; } u;
    u.h = __float2bfloat16(x);
    return u.s;
}

__device__ inline void async_load16(void* lds, const void* g) {
    __builtin_amdgcn_global_load_lds(
        (const __attribute__((address_space(1))) unsigned int*)g,
        (__attribute__((address_space(3))) unsigned int*)lds, 16, 0, 0);
}

// ---------------- Kernel 0: prep = f16 convert (X, Ek) + Evt + W transpose --
#define NXCHUNK 393216   // 4096*768/8
#define NECHUNK 1032     // 129*64/8
#define NEVCHUNK 1280    // 64*160/8
#define NCONVB ((NXCHUNK + NECHUNK + NEVCHUNK + 255) / 256)   // 1548
#define NTRB   (144 * 3)                                      // 432
__global__ __launch_bounds__(256) void prep_kernel(
    const float* __restrict__ X, const float* __restrict__ Ek,
    const float* __restrict__ Ev,
    const float* __restrict__ Wq, const float* __restrict__ Wk, const float* __restrict__ Wv,
    _Float16* __restrict__ Xh, _Float16* __restrict__ Ekh, short* __restrict__ Evt,
    _Float16* __restrict__ Wtq, _Float16* __restrict__ Wtk, _Float16* __restrict__ Wtv)
{
    const int bidg = blockIdx.x;
    if (bidg < NCONVB) {
        int idx = bidg * 256 + threadIdx.x;
        if (idx < NXCHUNK + NECHUNK) {
            const float* src;
            _Float16* dst;
            if (idx < NXCHUNK) { src = X; dst = Xh; }
            else { idx -= NXCHUNK; src = Ek; dst = Ekh; }
            float4 a = ((const float4*)src)[idx * 2];
            float4 b = ((const float4*)src)[idx * 2 + 1];
            f16x8 o;
            o[0] = (_Float16)a.x; o[1] = (_Float16)a.y; o[2] = (_Float16)a.z; o[3] = (_Float16)a.w;
            o[4] = (_Float16)b.x; o[5] = (_Float16)b.y; o[6] = (_Float16)b.z; o[7] = (_Float16)b.w;
            ((f16x8*)dst)[idx] = o;
        } else if (idx < NXCHUNK + NECHUNK + NEVCHUNK) {
            idx -= NXCHUNK + NECHUNK;
            const int dim = idx / 20;
            const int r0  = (idx % 20) * 8;
            short8 o;
#pragma unroll
            for (int e = 0; e < 8; ++e) {
                int rel = r0 + e;
                float v = (rel < RK) ? Ev[(size_t)rel * HD + dim] : 0.0f;
                o[e] = f2bf(v);
            }
            *(short8*)&Evt[(size_t)dim * 160 + r0] = o;
        }
        return;
    }
    // ---- W transpose part ----
    const int bid2 = bidg - NCONVB;
    const int z = bid2 / 144;
    const int r = bid2 % 144;
    const float* __restrict__ W = (z == 0) ? Wq : (z == 1) ? Wk : Wv;
    _Float16* __restrict__ Wt   = (z == 0) ? Wtq : (z == 1) ? Wtk : Wtv;

    __shared__ float sT[64][65];
    const int t  = threadIdx.x;
    const int k0 = (r / 12) * 64;
    const int n0 = (r % 12) * 64;

    const int c  = (t & 15) * 4;
    const int kr = t >> 4;
#pragma unroll
    for (int rr = 0; rr < 4; ++rr) {
        float4 v = *(const float4*)&W[(size_t)(k0 + kr + rr * 16) * HDIM + n0 + c];
        sT[c + 0][kr + rr * 16] = v.x;
        sT[c + 1][kr + rr * 16] = v.y;
        sT[c + 2][kr + rr * 16] = v.z;
        sT[c + 3][kr + rr * 16] = v.w;
    }
    __syncthreads();
    const int rn = t >> 2;
    const int ck = (t & 3) * 16;
#pragma unroll
    for (int g = 0; g < 2; ++g) {
        f16x8 o;
#pragma unroll
        for (int e = 0; e < 8; ++e) o[e] = (_Float16)sT[rn][ck + g * 8 + e];
        *(f16x8*)&Wt[(size_t)(n0 + rn) * HDIM + k0 + ck + g * 8] = o;
    }
}

// ---------------- Kernel 1: QKV projection via f16 MFMA --------------------
// Q,K -> [bh][s][d] f16.  V -> TRANSPOSED [bh][d][s] bf16 (for direct PV B-frags).
__global__ __launch_bounds__(256) void qkv_mfma_kernel(
    const _Float16* __restrict__ Xh,
    const _Float16* __restrict__ Wtq, const _Float16* __restrict__ Wtk, const _Float16* __restrict__ Wtv,
    const float* __restrict__ bq, const float* __restrict__ bk, const float* __restrict__ bv,
    _Float16* __restrict__ Qo, _Float16* __restrict__ Ko, short* __restrict__ Vt)
{
    int bid = blockIdx.x;
    bid = (bid & 7) * 72 + (bid >> 3);          // XCD swizzle (576 = 8*72)
    const int which = bid / 192;
    const int rem   = bid % 192;
    const int n0    = (rem / 32) * 128;
    const int m0    = (rem % 32) * 128;
    const _Float16* __restrict__ Wt = (which == 0) ? Wtq : (which == 1) ? Wtk : Wtv;
    const float* __restrict__ bias  = (which == 0) ? bq : (which == 1) ? bk : bv;

    __shared__ __align__(16) _Float16 sA[128 * 64];
    __shared__ __align__(16) _Float16 sB[128 * 64];

    const int t  = threadIdx.x;
    const int w  = t >> 6, l = t & 63;
    const int lq = l & 15, lg = l >> 4;
    const int wr = w >> 1, wc = w & 1;

    f32x4 acc[4][4];
#pragma unroll
    for (int i = 0; i < 4; ++i)
#pragma unroll
        for (int j = 0; j < 4; ++j) acc[i][j] = (f32x4){0.f, 0.f, 0.f, 0.f};

    for (int k0 = 0; k0 < HDIM; k0 += 64) {
        __syncthreads();
#pragma unroll
        for (int r = 0; r < 4; ++r) {
            const int cib = r * 256 + w * 64;
            const int ci  = cib + l;
            const int row = ci >> 3, cr = ci & 7;
            const int lc  = cr ^ (row & 7);
            async_load16(&sA[(size_t)cib * 8],
                         &Xh[(size_t)(m0 + row) * HDIM + k0 + lc * 8]);
            async_load16(&sB[(size_t)cib * 8],
                         &Wt[(size_t)(n0 + row) * HDIM + k0 + lc * 8]);
        }
        __syncthreads();

        f16x8 af[4][2], bf[4][2];
#pragma unroll
        for (int i = 0; i < 4; ++i) {
#pragma unroll
            for (int ks = 0; ks < 2; ++ks) {
                int ra = wr * 64 + i * 16 + lq;
                af[i][ks] = *(const f16x8*)((const char*)sA +
                            ra * 128 + ((ks * 64 + lg * 16) ^ ((ra & 7) << 4)));
                int rb = wc * 64 + i * 16 + lq;
                bf[i][ks] = *(const f16x8*)((const char*)sB +
                            rb * 128 + ((ks * 64 + lg * 16) ^ ((rb & 7) << 4)));
            }
        }
#pragma unroll
        for (int i = 0; i < 4; ++i)
#pragma unroll
            for (int j = 0; j < 4; ++j) {
                acc[i][j] = __builtin_amdgcn_mfma_f32_16x16x32_f16(af[i][0], bf[j][0], acc[i][j], 0, 0, 0);
                acc[i][j] = __builtin_amdgcn_mfma_f32_16x16x32_f16(af[i][1], bf[j][1], acc[i][j], 0, 0, 0);
            }
    }

    _Float16* __restrict__ Yh = (which == 0) ? Qo : Ko;
#pragma unroll
    for (int i = 0; i < 4; ++i) {
        const int mb = m0 + wr * 64 + i * 16 + lg * 4;
        const int bb = mb >> 10, ss = mb & 1023;
#pragma unroll
        for (int j = 0; j < 4; ++j) {
            const int n  = n0 + wc * 64 + j * 16 + lq;
            const float bv4 = bias[n];
            const int hh = n >> 6, dd = n & 63;
            if (which == 2) {
                short4v pk;
#pragma unroll
                for (int reg = 0; reg < 4; ++reg)
                    pk[reg] = f2bf(acc[i][j][reg] + bv4);
                *(short4v*)&Vt[((size_t)(bb * NH + hh) * HD + dd) * SEQ + ss] = pk;
            } else {
#pragma unroll
                for (int reg = 0; reg < 4; ++reg) {
                    const size_t off = ((size_t)(bb * NH + hh) * SEQ + ss + reg) * HD + dd;
                    Yh[off] = (_Float16)(acc[i][j][reg] + bv4);
                }
            }
        }
    }
}

// ---------------- Kernel 2: 1-wave-per-block MFMA flash attention ----------
// Each 64-thread block = ONE wave owning 16 q-rows. All LDS is wave-private
// (10.6 KB/block -> ~15 blocks/CU). K / V^T / mask read direct from global
// (L2-resident; XCD-chunked swizzle keeps a head's K/V in one XCD's L2).
// No __syncthreads anywhere.
__global__ __launch_bounds__(64, 4) void attn_mfma_kernel(
    const _Float16* __restrict__ Q, const _Float16* __restrict__ K,
    const short* __restrict__ Vt, const float* __restrict__ mask,
    const _Float16* __restrict__ Ekh, const short* __restrict__ Evt,
    float* __restrict__ out)
{
    __shared__ __align__(16) short sPscr[16][36];     // bf16 probs (PV A-frag)
    __shared__ __align__(16) _Float16 sPpos[16][132]; // Q@Ek^T
    __shared__ __align__(16) short sBand[16][162];    // bf16 band probs, rel-aligned

    // XCD-chunked swizzle: 3072 blocks = 8 XCDs x 384; consecutive original
    // ids (same head) land on the same XCD -> K/V stays in its 4MB L2.
    int bid = blockIdx.x;
    bid = (bid & 7) * 384 + (bid >> 3);
    const int bh    = bid >> 6;          // 0..47
    const int wrow0 = (bid & 63) * 16;   // q-row base
    const int b     = bh / NH;
    const int h     = bh - b * NH;

    const int l  = threadIdx.x;
    const int lq = l & 15;
    const int lg = l >> 4;

    // zero band buffer (flat 2592 shorts = 324 short8)
    {
        short8 z8 = {0, 0, 0, 0, 0, 0, 0, 0};
        short8* p = (short8*)&sBand[0][0];
        for (int idx = l; idx < 324; idx += 64) p[idx] = z8;
    }

    const _Float16* qp = Q + ((size_t)bh * SEQ + wrow0 + lq) * HD;
    f16x8 qf0 = *(const f16x8*)&qp[lg * 8];
    f16x8 qf1 = *(const f16x8*)&qp[32 + lg * 8];

    // P_pos = Q @ E_key^T
#pragma unroll
    for (int nt = 0; nt < 9; ++nt) {
        int cc = nt * 16 + lq;
        f16x8 eb0 = {0, 0, 0, 0, 0, 0, 0, 0};
        f16x8 eb1 = {0, 0, 0, 0, 0, 0, 0, 0};
        if (cc < RK) {
            eb0 = *(const f16x8*)&Ekh[(size_t)cc * HD + lg * 8];
            eb1 = *(const f16x8*)&Ekh[(size_t)cc * HD + 32 + lg * 8];
        }
        f32x4 pc = {0.f, 0.f, 0.f, 0.f};
        pc = __builtin_amdgcn_mfma_f32_16x16x32_f16(qf0, eb0, pc, 0, 0, 0);
        pc = __builtin_amdgcn_mfma_f32_16x16x32_f16(qf1, eb1, pc, 0, 0, 0);
        if (cc < 132) {
#pragma unroll
            for (int reg = 0; reg < 4; ++reg)
                sPpos[lg * 4 + reg][cc] = (_Float16)pc[reg];
        }
    }

    f32x4 acc[4];
#pragma unroll
    for (int nt = 0; nt < 4; ++nt) acc[nt] = (f32x4){0.f, 0.f, 0.f, 0.f};
    float lacc[4] = {0.f, 0.f, 0.f, 0.f};

    const _Float16* kp = K + ((size_t)bh * SEQ + lq) * HD + lg * 8;
    const short*    vp = Vt + ((size_t)bh * HD + lq) * SEQ + lg * 8;
    const float*    mp = mask + (size_t)b * SEQ + lq;

    for (int jt = 0; jt < SEQ / 32; ++jt) {
        const int j0 = jt * 32;
        // all of this tile's loads issue up front; waits land at first use
        f16x8 kb00 = *(const f16x8*)&kp[0];
        f16x8 kb01 = *(const f16x8*)&kp[32];
        f16x8 kb10 = *(const f16x8*)&kp[16 * HD];
        f16x8 kb11 = *(const f16x8*)&kp[16 * HD + 32];
        short8 vb0 = *(const short8*)&vp[0];
        short8 vb1 = *(const short8*)&vp[16 * SEQ];
        short8 vb2 = *(const short8*)&vp[32 * SEQ];
        short8 vb3 = *(const short8*)&vp[48 * SEQ];
        const float mt0 = (1.0f - mp[0])  * FMIN;
        const float mt1 = (1.0f - mp[16]) * FMIN;
        kp += 32 * HD; vp += 32; mp += 32;

        f32x4 sc0 = {0.f, 0.f, 0.f, 0.f};
        f32x4 sc1 = {0.f, 0.f, 0.f, 0.f};
        sc0 = __builtin_amdgcn_mfma_f32_16x16x32_f16(qf0, kb00, sc0, 0, 0, 0);
        sc0 = __builtin_amdgcn_mfma_f32_16x16x32_f16(qf1, kb01, sc0, 0, 0, 0);
        sc1 = __builtin_amdgcn_mfma_f32_16x16x32_f16(qf0, kb10, sc1, 0, 0, 0);
        sc1 = __builtin_amdgcn_mfma_f32_16x16x32_f16(qf1, kb11, sc1, 0, 0, 0);

        const bool band_active = (j0 + 31 >= wrow0 - 64) && (j0 <= wrow0 + 15 + 64);
        if (band_active) {
#pragma unroll
            for (int ct = 0; ct < 2; ++ct) {
                const f32x4 sc = ct ? sc1 : sc0;
                const float mt = ct ? mt1 : mt0;
                const int relb = j0 + ct * 16 + lq - wrow0 - lg * 4 + 64;
#pragma unroll
                for (int reg = 0; reg < 4; ++reg) {
                    const int row = lg * 4 + reg;
                    const int rel = relb - reg;
                    float s = sc[reg] + mt;
                    const bool inb = ((unsigned)rel < (unsigned)RK);
                    if (inb) s += (float)sPpos[row][rel];
                    const float p = __expf(s);
                    lacc[reg] += p;
                    const short pb = f2bf(p);
                    sPscr[row][ct * 16 + lq] = pb;
                    if (inb) sBand[row][rel] = pb;
                }
            }
        } else {
#pragma unroll
            for (int ct = 0; ct < 2; ++ct) {
                const f32x4 sc = ct ? sc1 : sc0;
                const float mt = ct ? mt1 : mt0;
#pragma unroll
                for (int reg = 0; reg < 4; ++reg) {
                    const float p = __expf(sc[reg] + mt);
                    lacc[reg] += p;
                    sPscr[lg * 4 + reg][ct * 16 + lq] = f2bf(p);
                }
            }
        }

        // PV (wave-internal LDS RAW; compiler inserts lgkmcnt waits)
        short8 pa = *(const short8*)&sPscr[lq][lg * 8];
        acc[0] = __builtin_amdgcn_mfma_f32_16x16x32_bf16(pa, vb0, acc[0], 0, 0, 0);
        acc[1] = __builtin_amdgcn_mfma_f32_16x16x32_bf16(pa, vb1, acc[1], 0, 0, 0);
        acc[2] = __builtin_amdgcn_mfma_f32_16x16x32_bf16(pa, vb2, acc[2], 0, 0, 0);
        acc[3] = __builtin_amdgcn_mfma_f32_16x16x32_bf16(pa, vb3, acc[3], 0, 0, 0);
    }

    float linv[4];
#pragma unroll
    for (int reg = 0; reg < 4; ++reg) {
        float lr = lacc[reg];
        lr += __shfl_xor(lr, 1);
        lr += __shfl_xor(lr, 2);
        lr += __shfl_xor(lr, 4);
        lr += __shfl_xor(lr, 8);
        linv[reg] = 1.0f / lr;
    }

    // band value term via MFMA: acc[nt] += bandP[16x160] @ Evt^T[160x64]
    short8 bandA[5];
#pragma unroll
    for (int ks = 0; ks < 5; ++ks)
        bandA[ks] = *(const short8*)&sBand[lq][ks * 32 + lg * 8];
#pragma unroll
    for (int nt = 0; nt < 4; ++nt) {
#pragma unroll
        for (int ks = 0; ks < 5; ++ks) {
            short8 eb = *(const short8*)&Evt[(size_t)(nt * 16 + lq) * 160 + ks * 32 + lg * 8];
            acc[nt] = __builtin_amdgcn_mfma_f32_16x16x32_bf16(bandA[ks], eb, acc[nt], 0, 0, 0);
        }
    }

#pragma unroll
    for (int nt = 0; nt < 4; ++nt) {
#pragma unroll
        for (int reg = 0; reg < 4; ++reg) {
            int qi = wrow0 + lg * 4 + reg;
            out[((size_t)b * SEQ + qi) * HDIM + h * HD + nt * 16 + lq] =
                acc[nt][reg] * linv[reg];
        }
    }
}

extern "C" void kernel_launch(void* const* d_in, const int* in_sizes, int n_in,
                              void* d_out, int out_size, void* d_ws, size_t ws_size,
                              hipStream_t stream) {
    const float* X    = (const float*)d_in[0];
    const float* mask = (const float*)d_in[1];
    const float* Wq   = (const float*)d_in[2];
    const float* bq   = (const float*)d_in[3];
    const float* Wk   = (const float*)d_in[4];
    const float* bk   = (const float*)d_in[5];
    const float* Wv   = (const float*)d_in[6];
    const float* bv   = (const float*)d_in[7];
    const float* Ek   = (const float*)d_in[8];
    const float* Ev   = (const float*)d_in[9];
    float* out        = (float*)d_out;

    char* ws = (char*)d_ws;
    const size_t SZ_QKV = (size_t)BSZ * NH * SEQ * HD * 2;   // 6,291,456 B each
    const size_t SZ_W   = (size_t)HDIM * HDIM * 2;           // 1,179,648 B each
    _Float16* Qh  = (_Float16*)(ws);
    _Float16* Kh  = (_Float16*)(ws + SZ_QKV);
    short*    Vt  = (short*)   (ws + 2 * SZ_QKV);            // [bh][d][s] bf16
    _Float16* Xh  = (_Float16*)(ws + 3 * SZ_QKV);
    _Float16* Wtq = (_Float16*)(ws + 4 * SZ_QKV);
    _Float16* Wtk = (_Float16*)(ws + 4 * SZ_QKV + SZ_W);
    _Float16* Wtv = (_Float16*)(ws + 4 * SZ_QKV + 2 * SZ_W);
    _Float16* Ekh = (_Float16*)(ws + 4 * SZ_QKV + 3 * SZ_W);
    short*    Evt = (short*)   (ws + 4 * SZ_QKV + 3 * SZ_W + 20480);

    prep_kernel<<<NCONVB + NTRB, 256, 0, stream>>>(
        X, Ek, Ev, Wq, Wk, Wv, Xh, Ekh, Evt, Wtq, Wtk, Wtv);
    qkv_mfma_kernel<<<576, 256, 0, stream>>>(Xh, Wtq, Wtk, Wtv, bq, bk, bv, Qh, Kh, Vt);
    attn_mfma_kernel<<<BSZ * NH * (SEQ / 16), 64, 0, stream>>>(Qh, Kh, Vt, mask, Ekh, Evt, out);
}

// Round 8
// 88.978 us; speedup vs baseline: 1.5285x; 1.5152x over previous
//
#include <hip/hip_runtime.h>
#include <hip/hip_bf16.h>
#include <math.h>

#define NH 12
#define SEQ 1024
#define HD 64
#define HDIM 768
#define BSZ 4
#define RK 129
#define FMIN -3.4028234663852886e38f

typedef __attribute__((ext_vector_type(8))) short short8;
typedef __attribute__((ext_vector_type(4))) short short4v;
typedef __attribute__((ext_vector_type(8))) _Float16 f16x8;
typedef __attribute__((ext_vector_type(4))) float f32x4;

__device__ inline short f2bf(float x) {
    union { __hip_bfloat16 h; short s; } u;
    u.h = __float2bfloat16(x);
    return u.s;
}
__device__ inline float bf2f(short s) {
    union { __hip_bfloat16 h; short t; } u;
    u.t = s;
    return __bfloat162float(u.h);
}

__device__ inline void async_load16(void* lds, const void* g) {
    __builtin_amdgcn_global_load_lds(
        (const __attribute__((address_space(1))) unsigned int*)g,
        (__attribute__((address_space(3))) unsigned int*)lds, 16, 0, 0);
}

#define BAR()    asm volatile("s_barrier" ::: "memory")
#define WAITV0() asm volatile("s_waitcnt vmcnt(0)" ::: "memory")

// ---------------- Kernel 0: prep = f16 convert (X, Ek) + Evt + W transpose --
#define NXCHUNK 393216   // 4096*768/8
#define NECHUNK 1032     // 129*64/8
#define NEVCHUNK 1280    // 64*160/8
#define NCONVB ((NXCHUNK + NECHUNK + NEVCHUNK + 255) / 256)   // 1548
#define NTRB   (144 * 3)                                      // 432
__global__ __launch_bounds__(256) void prep_kernel(
    const float* __restrict__ X, const float* __restrict__ Ek,
    const float* __restrict__ Ev,
    const float* __restrict__ Wq, const float* __restrict__ Wk, const float* __restrict__ Wv,
    _Float16* __restrict__ Xh, _Float16* __restrict__ Ekh, short* __restrict__ Evt,
    _Float16* __restrict__ Wtq, _Float16* __restrict__ Wtk, _Float16* __restrict__ Wtv)
{
    const int bidg = blockIdx.x;
    if (bidg < NCONVB) {
        int idx = bidg * 256 + threadIdx.x;
        if (idx < NXCHUNK + NECHUNK) {
            const float* src;
            _Float16* dst;
            if (idx < NXCHUNK) { src = X; dst = Xh; }
            else { idx -= NXCHUNK; src = Ek; dst = Ekh; }
            float4 a = ((const float4*)src)[idx * 2];
            float4 b = ((const float4*)src)[idx * 2 + 1];
            f16x8 o;
            o[0] = (_Float16)a.x; o[1] = (_Float16)a.y; o[2] = (_Float16)a.z; o[3] = (_Float16)a.w;
            o[4] = (_Float16)b.x; o[5] = (_Float16)b.y; o[6] = (_Float16)b.z; o[7] = (_Float16)b.w;
            ((f16x8*)dst)[idx] = o;
        } else if (idx < NXCHUNK + NECHUNK + NEVCHUNK) {
            idx -= NXCHUNK + NECHUNK;
            const int dim = idx / 20;
            const int r0  = (idx % 20) * 8;
            short8 o;
#pragma unroll
            for (int e = 0; e < 8; ++e) {
                int rel = r0 + e;
                float v = (rel < RK) ? Ev[(size_t)rel * HD + dim] : 0.0f;
                o[e] = f2bf(v);
            }
            *(short8*)&Evt[(size_t)dim * 160 + r0] = o;
        }
        return;
    }
    const int bid2 = bidg - NCONVB;
    const int z = bid2 / 144;
    const int r = bid2 % 144;
    const float* __restrict__ W = (z == 0) ? Wq : (z == 1) ? Wk : Wv;
    _Float16* __restrict__ Wt   = (z == 0) ? Wtq : (z == 1) ? Wtk : Wtv;

    __shared__ float sT[64][65];
    const int t  = threadIdx.x;
    const int k0 = (r / 12) * 64;
    const int n0 = (r % 12) * 64;

    const int c  = (t & 15) * 4;
    const int kr = t >> 4;
#pragma unroll
    for (int rr = 0; rr < 4; ++rr) {
        float4 v = *(const float4*)&W[(size_t)(k0 + kr + rr * 16) * HDIM + n0 + c];
        sT[c + 0][kr + rr * 16] = v.x;
        sT[c + 1][kr + rr * 16] = v.y;
        sT[c + 2][kr + rr * 16] = v.z;
        sT[c + 3][kr + rr * 16] = v.w;
    }
    __syncthreads();
    const int rn = t >> 2;
    const int ck = (t & 3) * 16;
#pragma unroll
    for (int g = 0; g < 2; ++g) {
        f16x8 o;
#pragma unroll
        for (int e = 0; e < 8; ++e) o[e] = (_Float16)sT[rn][ck + g * 8 + e];
        *(f16x8*)&Wt[(size_t)(n0 + rn) * HDIM + k0 + ck + g * 8] = o;
    }
}

// ---------------- Kernel 1: QKV projection via f16 MFMA --------------------
__global__ __launch_bounds__(256) void qkv_mfma_kernel(
    const _Float16* __restrict__ Xh,
    const _Float16* __restrict__ Wtq, const _Float16* __restrict__ Wtk, const _Float16* __restrict__ Wtv,
    const float* __restrict__ bq, const float* __restrict__ bk, const float* __restrict__ bv,
    _Float16* __restrict__ Qo, _Float16* __restrict__ Ko, short* __restrict__ Vt)
{
    int bid = blockIdx.x;
    bid = (bid & 7) * 72 + (bid >> 3);          // XCD swizzle (576 = 8*72)
    const int which = bid / 192;
    const int rem   = bid % 192;
    const int n0    = (rem / 32) * 128;
    const int m0    = (rem % 32) * 128;
    const _Float16* __restrict__ Wt = (which == 0) ? Wtq : (which == 1) ? Wtk : Wtv;
    const float* __restrict__ bias  = (which == 0) ? bq : (which == 1) ? bk : bv;

    __shared__ __align__(16) _Float16 sA[128 * 64];
    __shared__ __align__(16) _Float16 sB[128 * 64];

    const int t  = threadIdx.x;
    const int w  = t >> 6, l = t & 63;
    const int lq = l & 15, lg = l >> 4;
    const int wr = w >> 1, wc = w & 1;

    f32x4 acc[4][4];
#pragma unroll
    for (int i = 0; i < 4; ++i)
#pragma unroll
        for (int j = 0; j < 4; ++j) acc[i][j] = (f32x4){0.f, 0.f, 0.f, 0.f};

    for (int k0 = 0; k0 < HDIM; k0 += 64) {
        __syncthreads();
#pragma unroll
        for (int r = 0; r < 4; ++r) {
            const int cib = r * 256 + w * 64;
            const int ci  = cib + l;
            const int row = ci >> 3, cr = ci & 7;
            const int lc  = cr ^ (row & 7);
            async_load16(&sA[(size_t)cib * 8],
                         &Xh[(size_t)(m0 + row) * HDIM + k0 + lc * 8]);
            async_load16(&sB[(size_t)cib * 8],
                         &Wt[(size_t)(n0 + row) * HDIM + k0 + lc * 8]);
        }
        __syncthreads();

        f16x8 af[4][2], bf[4][2];
#pragma unroll
        for (int i = 0; i < 4; ++i) {
#pragma unroll
            for (int ks = 0; ks < 2; ++ks) {
                int ra = wr * 64 + i * 16 + lq;
                af[i][ks] = *(const f16x8*)((const char*)sA +
                            ra * 128 + ((ks * 64 + lg * 16) ^ ((ra & 7) << 4)));
                int rb = wc * 64 + i * 16 + lq;
                bf[i][ks] = *(const f16x8*)((const char*)sB +
                            rb * 128 + ((ks * 64 + lg * 16) ^ ((rb & 7) << 4)));
            }
        }
#pragma unroll
        for (int i = 0; i < 4; ++i)
#pragma unroll
            for (int j = 0; j < 4; ++j) {
                acc[i][j] = __builtin_amdgcn_mfma_f32_16x16x32_f16(af[i][0], bf[j][0], acc[i][j], 0, 0, 0);
                acc[i][j] = __builtin_amdgcn_mfma_f32_16x16x32_f16(af[i][1], bf[j][1], acc[i][j], 0, 0, 0);
            }
    }

    _Float16* __restrict__ Yh = (which == 0) ? Qo : Ko;
#pragma unroll
    for (int i = 0; i < 4; ++i) {
        const int mb = m0 + wr * 64 + i * 16 + lg * 4;
        const int bb = mb >> 10, ss = mb & 1023;
#pragma unroll
        for (int j = 0; j < 4; ++j) {
            const int n  = n0 + wc * 64 + j * 16 + lq;
            const float bv4 = bias[n];
            const int hh = n >> 6, dd = n & 63;
            if (which == 2) {
                short4v pk;
#pragma unroll
                for (int reg = 0; reg < 4; ++reg)
                    pk[reg] = f2bf(acc[i][j][reg] + bv4);
                *(short4v*)&Vt[((size_t)(bb * NH + hh) * HD + dd) * SEQ + ss] = pk;
            } else {
#pragma unroll
                for (int reg = 0; reg < 4; ++reg) {
                    const size_t off = ((size_t)(bb * NH + hh) * SEQ + ss + reg) * HD + dd;
                    Yh[off] = (_Float16)(acc[i][j][reg] + bv4);
                }
            }
        }
    }
}

// ---------------- Kernel 2: 2-phase double-buffered MFMA flash attention ---
// 4 waves/block, 64 q-rows. 64-key tiles. K + V^T staged via global_load_lds
// (XOR-swizzled source, linear dest) into double buffers; ONE raw s_barrier
// per tile; prefetch loads fly across the whole compute phase (T3 template).
__global__ __launch_bounds__(256, 2) void attn_mfma_kernel(
    const _Float16* __restrict__ Q, const _Float16* __restrict__ K,
    const short* __restrict__ Vt, const float* __restrict__ mask,
    const _Float16* __restrict__ Ekh, const short* __restrict__ Evt,
    float* __restrict__ out)
{
    __shared__ __align__(16) _Float16 sK[2][64][64];    // 16 KB, swizzled chunks
    __shared__ __align__(16) short    sVT[2][64][64];   // 16 KB, V^T bf16
    __shared__ __align__(16) short    sPscr[4][16][64]; // 8 KB, swizzled probs
    __shared__ __align__(16) _Float16 sPpos[4][16][129];// 16.1 KB
    __shared__ __align__(16) short    sBand[4][16][160];// 20 KB
    __shared__ __align__(16) short    sMask[1024];      // 2 KB (bf16 mt terms)

    int bid = blockIdx.x;
    bid = (bid & 7) * 96 + (bid >> 3);   // XCD chunk: 768 = 8*96, same head same XCD
    const int bh = bid >> 4;             // 0..47
    const int i0 = (bid & 15) * 64;
    const int b  = bh / NH;
    const int h  = bh - b * NH;

    const int t  = threadIdx.x;
    const int w  = t >> 6;
    const int l  = t & 63;
    const int lq = l & 15;
    const int lg = l >> 4;
    const int wrow0 = i0 + w * 16;

    // ---- prologue ----
    {   // zero own band buffer (per-wave)
        short8 z8 = {0, 0, 0, 0, 0, 0, 0, 0};
        short8* p = (short8*)&sBand[w][0][0];
        for (int idx = l; idx < 320; idx += 64) p[idx] = z8;
    }
    // stage tile 0 into buffer 0
#pragma unroll
    for (int r = 0; r < 2; ++r) {
        const int ci = r * 256 + w * 64 + l;
        const int row = ci >> 3;
        const int lc  = (ci & 7) ^ (row & 7);
        async_load16((char*)sK + ci * 16,
                     K + ((size_t)bh * SEQ + row) * HD + lc * 8);
        async_load16((char*)sVT + ci * 16,
                     Vt + ((size_t)bh * HD + row) * SEQ + lc * 8);
    }

    const _Float16* qp = Q + ((size_t)bh * SEQ + wrow0 + lq) * HD;
    f16x8 qf0 = *(const f16x8*)&qp[lg * 8];
    f16x8 qf1 = *(const f16x8*)&qp[32 + lg * 8];

    // P_pos = Q @ E_key^T (per-wave)
#pragma unroll
    for (int nt = 0; nt < 9; ++nt) {
        int cc = nt * 16 + lq;
        f16x8 eb0 = {0, 0, 0, 0, 0, 0, 0, 0};
        f16x8 eb1 = {0, 0, 0, 0, 0, 0, 0, 0};
        if (cc < RK) {
            eb0 = *(const f16x8*)&Ekh[(size_t)cc * HD + lg * 8];
            eb1 = *(const f16x8*)&Ekh[(size_t)cc * HD + 32 + lg * 8];
        }
        f32x4 pc = {0.f, 0.f, 0.f, 0.f};
        pc = __builtin_amdgcn_mfma_f32_16x16x32_f16(qf0, eb0, pc, 0, 0, 0);
        pc = __builtin_amdgcn_mfma_f32_16x16x32_f16(qf1, eb1, pc, 0, 0, 0);
        if (cc < RK) {
#pragma unroll
            for (int reg = 0; reg < 4; ++reg)
                sPpos[w][lg * 4 + reg][cc] = (_Float16)pc[reg];
        }
    }

    // mask -> LDS as bf16 additive terms
    {
        float4 mv = *(const float4*)&mask[(size_t)b * SEQ + t * 4];
        short4v mo;
        mo[0] = f2bf((1.0f - mv.x) * FMIN);
        mo[1] = f2bf((1.0f - mv.y) * FMIN);
        mo[2] = f2bf((1.0f - mv.z) * FMIN);
        mo[3] = f2bf((1.0f - mv.w) * FMIN);
        *(short4v*)&sMask[t * 4] = mo;
    }

    asm volatile("s_waitcnt vmcnt(0) lgkmcnt(0)" ::: "memory");
    BAR();

    f32x4 acc[4];
#pragma unroll
    for (int nt = 0; nt < 4; ++nt) acc[nt] = (f32x4){0.f, 0.f, 0.f, 0.f};
    float lacc[4] = {0.f, 0.f, 0.f, 0.f};

    const int ck0 = lg ^ (lq & 7);        // swizzled 16B-chunk, k-half 0
    const int ck1 = (4 + lg) ^ (lq & 7);  // k-half 1
    short* sPw = &sPscr[w][0][0];

    // ---- main loop: 16 tiles of 64 keys, one barrier each ----
    for (int jt = 0; jt < 16; ++jt) {
        const int cur = jt & 1;
        const int j0  = jt * 64;

        if (jt < 15) {  // stage next tile into the other buffer
            const int jn0 = j0 + 64;
#pragma unroll
            for (int r = 0; r < 2; ++r) {
                const int ci = r * 256 + w * 64 + l;
                const int row = ci >> 3;
                const int lc  = (ci & 7) ^ (row & 7);
                async_load16((char*)sK + (cur ^ 1) * 8192 + ci * 16,
                             K + ((size_t)bh * SEQ + jn0 + row) * HD + lc * 8);
                async_load16((char*)sVT + (cur ^ 1) * 8192 + ci * 16,
                             Vt + ((size_t)bh * HD + row) * SEQ + jn0 + lc * 8);
            }
        }

        // QK^T: 8 ds_read_b128 + 8 MFMA
        const char* sKc = (const char*)sK + cur * 8192;
        f32x4 sc[4];
#pragma unroll
        for (int ct = 0; ct < 4; ++ct) {
            const int rb = (ct * 16 + lq) * 128;
            f16x8 kb0 = *(const f16x8*)(sKc + rb + ck0 * 16);
            f16x8 kb1 = *(const f16x8*)(sKc + rb + ck1 * 16);
            f32x4 s = {0.f, 0.f, 0.f, 0.f};
            s = __builtin_amdgcn_mfma_f32_16x16x32_f16(qf0, kb0, s, 0, 0, 0);
            s = __builtin_amdgcn_mfma_f32_16x16x32_f16(qf1, kb1, s, 0, 0, 0);
            sc[ct] = s;
        }

        // softmax numerator + band scatter
        float mt[4];
#pragma unroll
        for (int ct = 0; ct < 4; ++ct) mt[ct] = bf2f(sMask[j0 + ct * 16 + lq]);

        const bool band_active = (j0 >= wrow0 - 127) && (j0 <= wrow0 + 79);
        if (band_active) {
#pragma unroll
            for (int ct = 0; ct < 4; ++ct) {
                const int relb = j0 + ct * 16 + lq - wrow0 - lg * 4 + 64;
#pragma unroll
                for (int reg = 0; reg < 4; ++reg) {
                    const int row = lg * 4 + reg;
                    const int rel = relb - reg;
                    float s = sc[ct][reg] + mt[ct];
                    const bool inb = ((unsigned)rel < (unsigned)RK);
                    if (inb) s += (float)sPpos[w][row][rel];
                    const float p = __expf(s);
                    lacc[reg] += p;
                    const short pb = f2bf(p);
                    sPw[row * 64 + ((ct * 16 + lq) ^ ((row & 7) << 3))] = pb;
                    if (inb) sBand[w][row][rel] = pb;
                }
            }
        } else {
#pragma unroll
            for (int ct = 0; ct < 4; ++ct) {
#pragma unroll
                for (int reg = 0; reg < 4; ++reg) {
                    const int row = lg * 4 + reg;
                    const float p = __expf(sc[ct][reg] + mt[ct]);
                    lacc[reg] += p;
                    sPw[row * 64 + ((ct * 16 + lq) ^ ((row & 7) << 3))] = f2bf(p);
                }
            }
        }

        // PV: 2 + 8 ds_read + 8 MFMA
        short8 pa0 = *(const short8*)((const char*)sPw + lq * 128 + ck0 * 16);
        short8 pa1 = *(const short8*)((const char*)sPw + lq * 128 + ck1 * 16);
        const char* sVc = (const char*)sVT + cur * 8192;
#pragma unroll
        for (int nt = 0; nt < 4; ++nt) {
            const int rb = (nt * 16 + lq) * 128;
            short8 vb0 = *(const short8*)(sVc + rb + ck0 * 16);
            short8 vb1 = *(const short8*)(sVc + rb + ck1 * 16);
            acc[nt] = __builtin_amdgcn_mfma_f32_16x16x32_bf16(pa0, vb0, acc[nt], 0, 0, 0);
            acc[nt] = __builtin_amdgcn_mfma_f32_16x16x32_bf16(pa1, vb1, acc[nt], 0, 0, 0);
        }

        WAITV0();   // next tile's DMA landed (had the whole compute to fly)
        BAR();      // all waves' DMA landed; all waves done reading cur
    }

    // ---- epilogue ----
    float linv[4];
#pragma unroll
    for (int reg = 0; reg < 4; ++reg) {
        float lr = lacc[reg];
        lr += __shfl_xor(lr, 1);
        lr += __shfl_xor(lr, 2);
        lr += __shfl_xor(lr, 4);
        lr += __shfl_xor(lr, 8);
        linv[reg] = 1.0f / lr;
    }

    // band value term via MFMA: acc[nt] += bandP[16x160] @ Evt^T[160x64]
    short8 bandA[5];
#pragma unroll
    for (int ks = 0; ks < 5; ++ks)
        bandA[ks] = *(const short8*)&sBand[w][lq][ks * 32 + lg * 8];
#pragma unroll
    for (int nt = 0; nt < 4; ++nt) {
#pragma unroll
        for (int ks = 0; ks < 5; ++ks) {
            short8 eb = *(const short8*)&Evt[(size_t)(nt * 16 + lq) * 160 + ks * 32 + lg * 8];
            acc[nt] = __builtin_amdgcn_mfma_f32_16x16x32_bf16(bandA[ks], eb, acc[nt], 0, 0, 0);
        }
    }

#pragma unroll
    for (int nt = 0; nt < 4; ++nt) {
#pragma unroll
        for (int reg = 0; reg < 4; ++reg) {
            int qi = wrow0 + lg * 4 + reg;
            out[((size_t)b * SEQ + qi) * HDIM + h * HD + nt * 16 + lq] =
                acc[nt][reg] * linv[reg];
        }
    }
}

extern "C" void kernel_launch(void* const* d_in, const int* in_sizes, int n_in,
                              void* d_out, int out_size, void* d_ws, size_t ws_size,
                              hipStream_t stream) {
    const float* X    = (const float*)d_in[0];
    const float* mask = (const float*)d_in[1];
    const float* Wq   = (const float*)d_in[2];
    const float* bq   = (const float*)d_in[3];
    const float* Wk   = (const float*)d_in[4];
    const float* bk   = (const float*)d_in[5];
    const float* Wv   = (const float*)d_in[6];
    const float* bv   = (const float*)d_in[7];
    const float* Ek   = (const float*)d_in[8];
    const float* Ev   = (const float*)d_in[9];
    float* out        = (float*)d_out;

    char* ws = (char*)d_ws;
    const size_t SZ_QKV = (size_t)BSZ * NH * SEQ * HD * 2;   // 6,291,456 B each
    const size_t SZ_W   = (size_t)HDIM * HDIM * 2;           // 1,179,648 B each
    _Float16* Qh  = (_Float16*)(ws);
    _Float16* Kh  = (_Float16*)(ws + SZ_QKV);
    short*    Vt  = (short*)   (ws + 2 * SZ_QKV);            // [bh][d][s] bf16
    _Float16* Xh  = (_Float16*)(ws + 3 * SZ_QKV);
    _Float16* Wtq = (_Float16*)(ws + 4 * SZ_QKV);
    _Float16* Wtk = (_Float16*)(ws + 4 * SZ_QKV + SZ_W);
    _Float16* Wtv = (_Float16*)(ws + 4 * SZ_QKV + 2 * SZ_W);
    _Float16* Ekh = (_Float16*)(ws + 4 * SZ_QKV + 3 * SZ_W);
    short*    Evt = (short*)   (ws + 4 * SZ_QKV + 3 * SZ_W + 20480);

    prep_kernel<<<NCONVB + NTRB, 256, 0, stream>>>(
        X, Ek, Ev, Wq, Wk, Wv, Xh, Ekh, Evt, Wtq, Wtk, Wtv);
    qkv_mfma_kernel<<<576, 256, 0, stream>>>(Xh, Wtq, Wtk, Wtv, bq, bk, bv, Qh, Kh, Vt);
    attn_mfma_kernel<<<768, 256, 0, stream>>>(Qh, Kh, Vt, mask, Ekh, Evt, out);
}